// Round 18
// baseline (339.102 us; speedup 1.0000x reference)
//
#include <hip/hip_runtime.h>
#include <hip/hip_fp16.h>

#define N_NODES   50000
#define N_EDGES   800000
#define NUM_GRAPHS 256
#define IN_FEAT   64
#define REL_DIM   32
#define HID       128
#define NUM_RELS  32
#define NUM_BASES 8
#define NUM_LAYERS 2

#define NBUCK 196            // dst >> 8
#define PBLK  512            // scatter blocks
#define CHUNK 1563           // ceil(800000/512)
#define OFFN  (NBUCK * PBLK) // 100352
#define SC2_BLKS (OFFN / 256)  // 392

typedef __attribute__((ext_vector_type(8))) _Float16 f16x8;
typedef __attribute__((ext_vector_type(4))) float f32x4;
typedef __attribute__((ext_vector_type(2))) float f32x2;

// ---------------- edge sort phase A: per-(block,bucket) histogram ----------------
__global__ void __launch_bounds__(256) k_bhist(const int* __restrict__ dst,
                                               int* __restrict__ off) {
    __shared__ int hist[NBUCK];
    int t = threadIdx.x;
    if (t < NBUCK) hist[t] = 0;
    __syncthreads();
    int base = blockIdx.x * CHUNK;
    for (int i = t; i < CHUNK; i += 256) {
        int e = base + i;
        if (e < N_EDGES) atomicAdd(&hist[dst[e] >> 8], 1);
    }
    __syncthreads();
    if (t < NBUCK) off[t * PBLK + blockIdx.x] = hist[t];
}

// ---------------- phase B: multi-block exclusive scan of off[OFFN] ----------------
__global__ void __launch_bounds__(256) k_scan2_a(int* __restrict__ off,
                                                 int* __restrict__ bsum) {
    __shared__ int s[256];
    int t = threadIdx.x;
    int idx = blockIdx.x * 256 + t;
    int v = off[idx];
    s[t] = v;
    __syncthreads();
    for (int o = 1; o < 256; o <<= 1) {
        int u = (t >= o) ? s[t - o] : 0;
        __syncthreads();
        s[t] += u;
        __syncthreads();
    }
    off[idx] = s[t] - v;                 // local exclusive
    if (t == 255) bsum[blockIdx.x] = s[255];
}

__global__ void __launch_bounds__(512) k_scan2_b(int* __restrict__ bsum,
                                                 int* __restrict__ boff) {
    __shared__ int s[512];
    int t = threadIdx.x;
    int v = (t < SC2_BLKS) ? bsum[t] : 0;
    s[t] = v;
    __syncthreads();
    for (int o = 1; o < 512; o <<= 1) {
        int u = (t >= o) ? s[t - o] : 0;
        __syncthreads();
        s[t] += u;
        __syncthreads();
    }
    if (t < SC2_BLKS) boff[t] = s[t] - v;   // exclusive
}

__global__ void __launch_bounds__(256) k_scan2_c(int* __restrict__ off,
                                                 const int* __restrict__ boff) {
    int idx = blockIdx.x * 256 + threadIdx.x;
    off[idx] += boff[blockIdx.x];
}

// ---------------- phase C: bucket-scatter (packed (dl<<21)|(src<<5)|ety) ----------------
__global__ void __launch_bounds__(256) k_bscatter(
    const int* __restrict__ src, const int* __restrict__ dst,
    const int* __restrict__ ety, const int* __restrict__ off,
    int* __restrict__ tmp) {
    __shared__ int cur[NBUCK];
    int t = threadIdx.x;
    if (t < NBUCK) cur[t] = off[t * PBLK + blockIdx.x];
    __syncthreads();
    int base = blockIdx.x * CHUNK;
    for (int i = t; i < CHUNK; i += 256) {
        int e = base + i;
        if (e < N_EDGES) {
            int d = dst[e];
            int pos = atomicAdd(&cur[d >> 8], 1);
            tmp[pos] = ((d & 255) << 21) | (src[e] << 5) | ety[e];
        }
    }
}

// ---------------- phase D: per-bucket counting sort by dst_local; emits row_start ----------------
__global__ void __launch_bounds__(256) k_bsort(
    const int* __restrict__ off, const int* __restrict__ tmp,
    int* __restrict__ edge_p, int* __restrict__ row_start) {
    int b = blockIdx.x, t = threadIdx.x;
    int eb = off[b * PBLK];
    int ee = (b == NBUCK - 1) ? N_EDGES : off[(b + 1) * PBLK];
    __shared__ int cnt[256];
    __shared__ int cur[256];
    cnt[t] = 0;
    __syncthreads();
    for (int i = eb + t; i < ee; i += 256)
        atomicAdd(&cnt[(tmp[i] >> 21) & 255], 1);
    __syncthreads();
    int v = cnt[t];
    __shared__ int s[256];
    s[t] = v;
    __syncthreads();
    for (int o = 1; o < 256; o <<= 1) {
        int u = (t >= o) ? s[t - o] : 0;
        __syncthreads();
        s[t] += u;
        __syncthreads();
    }
    int excl = s[t] - v;
    cur[t] = eb + excl;
    int node = b * 256 + t;
    if (node < N_NODES) row_start[node] = eb + excl;
    if (b == NBUCK - 1 && t == 0) row_start[N_NODES] = N_EDGES;
    __syncthreads();
    for (int i = eb + t; i < ee; i += 256) {
        int x = tmp[i];
        int pos = atomicAdd(&cur[(x >> 21) & 255], 1);
        edge_p[pos] = x & 0x1FFFFF;      // (src<<5)|ety
    }
}

// ---------------- input projection (16 nodes/block): h16 = fp16(relu([feat, er] @ W_in + b_in)) ----------------
__global__ void __launch_bounds__(128) k_input(
    const float* __restrict__ feat, const int* __restrict__ qrel,
    const float* __restrict__ rel_emb, const float* __restrict__ Wi,
    const float* __restrict__ bi, unsigned short* __restrict__ h16,
    float* __restrict__ er) {
    int n0 = blockIdx.x * 16;
    int j = threadIdx.x;
    int u = j >> 3, q = j & 7;
    __shared__ float xT[96][16];
    {
        const float4* f4 = (const float4*)(feat + (size_t)(n0 + u) * IN_FEAT);
        float4 a = f4[q], b = f4[q + 8];
        xT[4 * q + 0][u] = a.x; xT[4 * q + 1][u] = a.y;
        xT[4 * q + 2][u] = a.z; xT[4 * q + 3][u] = a.w;
        xT[32 + 4 * q + 0][u] = b.x; xT[32 + 4 * q + 1][u] = b.y;
        xT[32 + 4 * q + 2][u] = b.z; xT[32 + 4 * q + 3][u] = b.w;
        int qr = qrel[n0 + u];
        float4 e4 = ((const float4*)(rel_emb + (size_t)qr * REL_DIM))[q];
        xT[64 + 4 * q + 0][u] = e4.x; xT[64 + 4 * q + 1][u] = e4.y;
        xT[64 + 4 * q + 2][u] = e4.z; xT[64 + 4 * q + 3][u] = e4.w;
        ((float4*)(er + (size_t)(n0 + u) * REL_DIM))[q] = e4;
    }
    __syncthreads();
    float bj = bi[j];
    float acc[16];
#pragma unroll
    for (int k = 0; k < 16; k++) acc[k] = bj;
    for (int d = 0; d < 96; d++) {
        float w = Wi[d * HID + j];
        float4 x0 = *(const float4*)&xT[d][0];
        float4 x1 = *(const float4*)&xT[d][4];
        float4 x2 = *(const float4*)&xT[d][8];
        float4 x3 = *(const float4*)&xT[d][12];
        acc[0]  = fmaf(x0.x, w, acc[0]);  acc[1]  = fmaf(x0.y, w, acc[1]);
        acc[2]  = fmaf(x0.z, w, acc[2]);  acc[3]  = fmaf(x0.w, w, acc[3]);
        acc[4]  = fmaf(x1.x, w, acc[4]);  acc[5]  = fmaf(x1.y, w, acc[5]);
        acc[6]  = fmaf(x1.z, w, acc[6]);  acc[7]  = fmaf(x1.w, w, acc[7]);
        acc[8]  = fmaf(x2.x, w, acc[8]);  acc[9]  = fmaf(x2.y, w, acc[9]);
        acc[10] = fmaf(x2.z, w, acc[10]); acc[11] = fmaf(x2.w, w, acc[11]);
        acc[12] = fmaf(x3.x, w, acc[12]); acc[13] = fmaf(x3.y, w, acc[13]);
        acc[14] = fmaf(x3.z, w, acc[14]); acc[15] = fmaf(x3.w, w, acc[15]);
    }
#pragma unroll
    for (int k = 0; k < 16; k++) {
        float v = fmaxf(acc[k], 0.f);
        __half hv = __float2half(v);
        h16[(size_t)(n0 + k) * HID + j] = __builtin_bit_cast(unsigned short, hv);
    }
}

// ---------------- FUSED layer: gather into LDS G-tile (fp16, frag order) + MFMA ----------------
// out16 = fp16(relu([G | h] @ f16([Vl ; Wl]) + bl)).
// Block = 512 thr (8 waves), 32 rows. LDS G-tile 64 frags x 1KB = 64KB.
// Frag F = b*8 + sb*2 + i  (sb = k-subgroup lane>>4, i = row>>4).
// Store slot (per row, lane): ((row&15)^qq)+16*qq, qq=(lane>>2)&3, j=2*(lane&3).
// Read: wave w -> t=w; A-frag at ushort (lane^((lane>>4)&3))*8 (verified mapping, R7).
__global__ void __launch_bounds__(512) k_fused2(
    const unsigned short* __restrict__ h16, const float* __restrict__ comp_l,
    const int* __restrict__ row_start, const int* __restrict__ edge_p,
    const unsigned short* __restrict__ Bf, const float* __restrict__ bl,
    unsigned short* __restrict__ out16) {
    __shared__ unsigned short Gt[64][512];        // 64 KB
    __shared__ f32x2 cs2[NUM_RELS * NUM_BASES];   // 2 KB
    int tid = threadIdx.x;
    int lane = tid & 63, w = tid >> 6;
    if (tid < NUM_RELS * NUM_BASES) {
        float c = comp_l[tid];
        cs2[tid] = (f32x2){c, c};
    }
    __syncthreads();
    int r0 = blockIdx.x * 32;

    // ---- phase A: wave w gathers nodes rloc = w*4..w*4+3, writes frag-order fp16 ----
    {
        int qq = (lane >> 2) & 3;
        int lo2 = lane & 3;
        int sb = lane >> 4;
#pragma unroll
        for (int u = 0; u < 4; u++) {
            int rloc = w * 4 + u;
            int n = r0 + rloc;
            f32x2 acc[NUM_BASES] = {};
            if (n < N_NODES) {
                int e0 = row_start[n], e1 = row_start[n + 1];
                int e = e0;
                for (; e + 8 <= e1; e += 8) {
                    int p0 = edge_p[e],     p1 = edge_p[e + 1];
                    int p2 = edge_p[e + 2], p3 = edge_p[e + 3];
                    int p4 = edge_p[e + 4], p5 = edge_p[e + 5];
                    int p6 = edge_p[e + 6], p7 = edge_p[e + 7];
                    unsigned u0 = ((const unsigned*)(h16 + (size_t)(p0 >> 5) * HID))[lane];
                    unsigned u1 = ((const unsigned*)(h16 + (size_t)(p1 >> 5) * HID))[lane];
                    unsigned u2 = ((const unsigned*)(h16 + (size_t)(p2 >> 5) * HID))[lane];
                    unsigned u3 = ((const unsigned*)(h16 + (size_t)(p3 >> 5) * HID))[lane];
                    unsigned u4 = ((const unsigned*)(h16 + (size_t)(p4 >> 5) * HID))[lane];
                    unsigned u5 = ((const unsigned*)(h16 + (size_t)(p5 >> 5) * HID))[lane];
                    unsigned u6 = ((const unsigned*)(h16 + (size_t)(p6 >> 5) * HID))[lane];
                    unsigned u7 = ((const unsigned*)(h16 + (size_t)(p7 >> 5) * HID))[lane];
                    const f32x2* c0p = &cs2[(p0 & 31) * NUM_BASES];
                    const f32x2* c1p = &cs2[(p1 & 31) * NUM_BASES];
                    const f32x2* c2p = &cs2[(p2 & 31) * NUM_BASES];
                    const f32x2* c3p = &cs2[(p3 & 31) * NUM_BASES];
                    const f32x2* c4p = &cs2[(p4 & 31) * NUM_BASES];
                    const f32x2* c5p = &cs2[(p5 & 31) * NUM_BASES];
                    const f32x2* c6p = &cs2[(p6 & 31) * NUM_BASES];
                    const f32x2* c7p = &cs2[(p7 & 31) * NUM_BASES];
                    float2 t0 = __half22float2(__builtin_bit_cast(__half2, u0));
                    float2 t1 = __half22float2(__builtin_bit_cast(__half2, u1));
                    float2 t2 = __half22float2(__builtin_bit_cast(__half2, u2));
                    float2 t3 = __half22float2(__builtin_bit_cast(__half2, u3));
                    float2 t4 = __half22float2(__builtin_bit_cast(__half2, u4));
                    float2 t5 = __half22float2(__builtin_bit_cast(__half2, u5));
                    float2 t6 = __half22float2(__builtin_bit_cast(__half2, u6));
                    float2 t7 = __half22float2(__builtin_bit_cast(__half2, u7));
                    f32x2 v0 = {t0.x, t0.y}, v1 = {t1.x, t1.y};
                    f32x2 v2 = {t2.x, t2.y}, v3 = {t3.x, t3.y};
                    f32x2 v4 = {t4.x, t4.y}, v5 = {t5.x, t5.y};
                    f32x2 v6 = {t6.x, t6.y}, v7 = {t7.x, t7.y};
#pragma unroll
                    for (int b = 0; b < NUM_BASES; b++) {
                        acc[b] += c0p[b] * v0;
                        acc[b] += c1p[b] * v1;
                        acc[b] += c2p[b] * v2;
                        acc[b] += c3p[b] * v3;
                        acc[b] += c4p[b] * v4;
                        acc[b] += c5p[b] * v5;
                        acc[b] += c6p[b] * v6;
                        acc[b] += c7p[b] * v7;
                    }
                }
                for (; e < e1; e++) {
                    int se = edge_p[e];
                    const f32x2* cp = &cs2[(se & 31) * NUM_BASES];
                    unsigned uu = ((const unsigned*)(h16 + (size_t)(se >> 5) * HID))[lane];
                    float2 tv = __half22float2(__builtin_bit_cast(__half2, uu));
                    f32x2 v = {tv.x, tv.y};
#pragma unroll
                    for (int b = 0; b < NUM_BASES; b++) acc[b] += cp[b] * v;
                }
            }
            int slotp = ((rloc & 15) ^ qq) + 16 * qq;
            int pos = slotp * 8 + lo2 * 2;
            int Fbase = sb * 2 + (rloc >> 4);
#pragma unroll
            for (int b = 0; b < NUM_BASES; b++) {
                __half2 g2 = __floats2half2_rn(acc[b][0], acc[b][1]);
                *(ushort2*)&Gt[b * 8 + Fbase][pos] =
                    __builtin_bit_cast(ushort2, g2);
            }
        }
    }
    __syncthreads();

    // ---- phase B: wave w computes cols [w*16, w*16+16) for 32 rows ----
    int rit = lane & 15, kg = lane >> 4;
    int slotr = (lane ^ ((lane >> 4) & 3)) * 8;   // ushort offset of this lane's 16B
    const f16x8* bb = (const f16x8*)Bf + (size_t)w * 64 + lane;  // (s=0, t=w)
    f32x4 acc0 = {}, acc1 = {};
#pragma unroll 4
    for (int s = 0; s < 32; s++) {
        f16x8 bh = bb[(size_t)s * 512];
        f16x8 a0 = *(const f16x8*)&Gt[s * 2 + 0][slotr];
        f16x8 a1 = *(const f16x8*)&Gt[s * 2 + 1][slotr];
        acc0 = __builtin_amdgcn_mfma_f32_16x16x32_f16(a0, bh, acc0, 0, 0, 0);
        acc1 = __builtin_amdgcn_mfma_f32_16x16x32_f16(a1, bh, acc1, 0, 0, 0);
    }
    // K tail 1024..1151 (self-loop) from h16
    {
        int rT0 = r0 + rit;      if (rT0 >= N_NODES) rT0 = N_NODES - 1;
        int rT1 = r0 + 16 + rit; if (rT1 >= N_NODES) rT1 = N_NODES - 1;
        const unsigned short* hp0 = h16 + (size_t)rT0 * HID + kg * 8;
        const unsigned short* hp1 = h16 + (size_t)rT1 * HID + kg * 8;
#pragma unroll
        for (int s = 32; s < 36; s++) {
            int o = (s - 32) * 32;
            f16x8 a0 = *(const f16x8*)(hp0 + o);
            f16x8 a1 = *(const f16x8*)(hp1 + o);
            f16x8 bh = bb[(size_t)s * 512];
            acc0 = __builtin_amdgcn_mfma_f32_16x16x32_f16(a0, bh, acc0, 0, 0, 0);
            acc1 = __builtin_amdgcn_mfma_f32_16x16x32_f16(a1, bh, acc1, 0, 0, 0);
        }
    }
    int col = w * 16 + rit;
    float bc = bl[col];
#pragma unroll
    for (int q = 0; q < 4; q++) {
        int rA = r0 + kg * 4 + q;
        if (rA < N_NODES) {
            float v = fmaxf(acc0[q] + bc, 0.f);
            out16[(size_t)rA * HID + col] =
                __builtin_bit_cast(unsigned short, __float2half(v));
        }
        int rB = rA + 16;
        if (rB < N_NODES) {
            float v = fmaxf(acc1[q] + bc, 0.f);
            out16[(size_t)rB * HID + col] =
                __builtin_bit_cast(unsigned short, __float2half(v));
        }
    }
}

// ---------------- B fragment table: f16 (hi only) of [Vl ; Wl], MFMA fragment order ----------------
__global__ void k_bfrag(const float* __restrict__ V, const float* __restrict__ W_loop,
                        unsigned short* __restrict__ Bf) {
    int idx = blockIdx.x * 256 + threadIdx.x;
    if (idx >= NUM_LAYERS * 36 * 8 * 64) return;
    int lane = idx & 63;
    int t = (idx >> 6) & 7;
    int s = (idx >> 9) % 36;
    int l = (idx >> 9) / 36;
    int col = t * 16 + (lane & 15);
    int kbase = s * 32 + (lane >> 4) * 8;
    unsigned short* o = Bf + (size_t)idx * 8;
#pragma unroll
    for (int j = 0; j < 8; j++) {
        int k = kbase + j;
        float f = (k < 1024) ? V[((size_t)l * 1024 + k) * HID + col]
                             : W_loop[((size_t)l * HID + (k - 1024)) * HID + col];
        __half hh = __float2half(f);
        o[j] = __builtin_bit_cast(unsigned short, hh);
    }
}

// ---------------- attention scalar score per node (16 nodes/block, h16 input) ----------------
__global__ void __launch_bounds__(128) k_score(
    const unsigned short* __restrict__ h16, const float* __restrict__ er,
    const float* __restrict__ Wa, const float* __restrict__ ba,
    const float* __restrict__ wsc, const float* __restrict__ bsc,
    float* __restrict__ a) {
    int n0 = blockIdx.x * 16;
    int j = threadIdx.x;
    int u = j >> 3, q = j & 7;
    __shared__ float xT[160][16];
    {
        const uint2* h2 = (const uint2*)(h16 + (size_t)(n0 + u) * HID);
#pragma unroll
        for (int k = 0; k < 4; k++) {
            uint2 v = h2[q + 8 * k];
            float2 f01 = __half22float2(__builtin_bit_cast(__half2, v.x));
            float2 f23 = __half22float2(__builtin_bit_cast(__half2, v.y));
            xT[32 * k + 4 * q + 0][u] = f01.x; xT[32 * k + 4 * q + 1][u] = f01.y;
            xT[32 * k + 4 * q + 2][u] = f23.x; xT[32 * k + 4 * q + 3][u] = f23.y;
        }
        float4 e4 = ((const float4*)(er + (size_t)(n0 + u) * REL_DIM))[q];
        xT[128 + 4 * q + 0][u] = e4.x; xT[128 + 4 * q + 1][u] = e4.y;
        xT[128 + 4 * q + 2][u] = e4.z; xT[128 + 4 * q + 3][u] = e4.w;
    }
    __syncthreads();
    float bj = ba[j];
    float acc[16];
#pragma unroll
    for (int k = 0; k < 16; k++) acc[k] = bj;
    for (int d = 0; d < 160; d++) {
        float w = Wa[d * HID + j];
        float4 x0 = *(const float4*)&xT[d][0];
        float4 x1 = *(const float4*)&xT[d][4];
        float4 x2 = *(const float4*)&xT[d][8];
        float4 x3 = *(const float4*)&xT[d][12];
        acc[0]  = fmaf(x0.x, w, acc[0]);  acc[1]  = fmaf(x0.y, w, acc[1]);
        acc[2]  = fmaf(x0.z, w, acc[2]);  acc[3]  = fmaf(x0.w, w, acc[3]);
        acc[4]  = fmaf(x1.x, w, acc[4]);  acc[5]  = fmaf(x1.y, w, acc[5]);
        acc[6]  = fmaf(x1.z, w, acc[6]);  acc[7]  = fmaf(x1.w, w, acc[7]);
        acc[8]  = fmaf(x2.x, w, acc[8]);  acc[9]  = fmaf(x2.y, w, acc[9]);
        acc[10] = fmaf(x2.z, w, acc[10]); acc[11] = fmaf(x2.w, w, acc[11]);
        acc[12] = fmaf(x3.x, w, acc[12]); acc[13] = fmaf(x3.y, w, acc[13]);
        acc[14] = fmaf(x3.z, w, acc[14]); acc[15] = fmaf(x3.w, w, acc[15]);
    }
    __shared__ float red[16][128];
    float wj = wsc[j];
#pragma unroll
    for (int k = 0; k < 16; k++) red[k][j] = tanhf(acc[k]) * wj;
    __syncthreads();
    for (int s = 64; s > 0; s >>= 1) {
        if (j < s) {
#pragma unroll
            for (int k = 0; k < 16; k++) red[k][j] += red[k][j + s];
        }
        __syncthreads();
    }
    if (j < 16) a[n0 + j] = red[j][0] + bsc[0];
}

// ---------------- graph boundaries (graph_id is sorted) ----------------
__global__ void k_starts(const int* __restrict__ gid, int* __restrict__ starts) {
    int g = threadIdx.x;  // 0..255
    int lo = 0, hi = N_NODES;
    while (lo < hi) {
        int mid = (lo + hi) >> 1;
        if (gid[mid] < g) lo = mid + 1; else hi = mid;
    }
    starts[g] = lo;
    if (g == 0) starts[NUM_GRAPHS] = N_NODES;
}

// ---------------- segment softmax pooling + final dot (h16 input) ----------------
__global__ void __launch_bounds__(128) k_pool(
    const unsigned short* __restrict__ h16, const float* __restrict__ a,
    const int* __restrict__ starts, const float* __restrict__ wout,
    const float* __restrict__ bout, float* __restrict__ out) {
    int g = blockIdx.x, j = threadIdx.x;
    int s0 = starts[g], s1 = starts[g + 1];
    __shared__ float red[128];
    __shared__ float exb[128];
    if (s1 <= s0) { if (j == 0) out[g] = bout[0]; return; }
    float m = -3.4e38f;
    for (int i = s0 + j; i < s1; i += 128) m = fmaxf(m, a[i]);
    red[j] = m; __syncthreads();
    for (int s = 64; s > 0; s >>= 1) {
        if (j < s) red[j] = fmaxf(red[j], red[j + s]);
        __syncthreads();
    }
    m = red[0]; __syncthreads();
    float zj = 0.f, ss = 0.f;
    for (int base = s0; base < s1; base += 128) {
        int cnt = min(128, s1 - base);
        float ev = 0.f;
        if (j < cnt) ev = expf(a[base + j] - m);
        exb[j] = ev;
        ss += ev;
        __syncthreads();
        for (int k = 0; k < cnt; k++) {
            __half hv = __builtin_bit_cast(__half, h16[(size_t)(base + k) * HID + j]);
            zj = fmaf(exb[k], __half2float(hv), zj);
        }
        __syncthreads();
    }
    red[j] = ss; __syncthreads();
    for (int s = 64; s > 0; s >>= 1) {
        if (j < s) red[j] += red[j + s];
        __syncthreads();
    }
    ss = red[0]; __syncthreads();
    red[j] = (zj / ss) * wout[j]; __syncthreads();
    for (int s = 64; s > 0; s >>= 1) {
        if (j < s) red[j] += red[j + s];
        __syncthreads();
    }
    if (j == 0) out[g] = red[0] + bout[0];
}

extern "C" void kernel_launch(void* const* d_in, const int* in_sizes, int n_in,
                              void* d_out, int out_size, void* d_ws, size_t ws_size,
                              hipStream_t stream) {
    const float* feat    = (const float*)d_in[0];
    const int*   qrel    = (const int*)d_in[1];
    const int*   src     = (const int*)d_in[2];
    const int*   dst     = (const int*)d_in[3];
    const int*   ety     = (const int*)d_in[4];
    const int*   gid     = (const int*)d_in[5];
    const float* rel_emb = (const float*)d_in[6];
    const float* W_in    = (const float*)d_in[7];
    const float* b_in    = (const float*)d_in[8];
    const float* V       = (const float*)d_in[9];
    const float* comp    = (const float*)d_in[10];
    const float* W_loop  = (const float*)d_in[11];
    const float* b_loop  = (const float*)d_in[12];
    const float* W_attn  = (const float*)d_in[13];
    const float* b_attn  = (const float*)d_in[14];
    const float* w_sc    = (const float*)d_in[15];
    const float* b_sc    = (const float*)d_in[16];
    const float* w_out   = (const float*)d_in[17];
    const float* b_out   = (const float*)d_in[18];
    float* out = (float*)d_out;

    float* ws = (float*)d_ws;
    unsigned short* h16a = (unsigned short*)ws;           // 6.4M ushort
    unsigned short* h16b = h16a + (size_t)N_NODES * HID;  // 6.4M ushort
    float* er = (float*)(h16b + (size_t)N_NODES * HID);   // 1.6M f32
    float* af = er + (size_t)N_NODES * REL_DIM;           // 50000
    int* starts    = (int*)(af + N_NODES);                // 260
    int* row_start = starts + 260;                        // 50004
    int* off       = row_start + 50004;                   // 100352
    int* bsum      = off + OFFN;                          // 392
    int* boff      = bsum + SC2_BLKS;                     // 392
    int* tmp_e     = boff + SC2_BLKS;                     // 800000
    int* edge_p    = tmp_e + 800000;                      // 800000
    unsigned short* Bf = (unsigned short*)(edge_p + 800000);  // 2*36*8*64*8 ushort

    // --- preprocessing: bucketed counting sort -> edge_p + row_start ---
    k_bhist<<<PBLK, 256, 0, stream>>>(dst, off);
    k_scan2_a<<<SC2_BLKS, 256, 0, stream>>>(off, bsum);
    k_scan2_b<<<1, 512, 0, stream>>>(bsum, boff);
    k_scan2_c<<<SC2_BLKS, 256, 0, stream>>>(off, boff);
    k_bscatter<<<PBLK, 256, 0, stream>>>(src, dst, ety, off, tmp_e);
    k_bsort<<<NBUCK, 256, 0, stream>>>(off, tmp_e, edge_p, row_start);
    k_bfrag<<<(NUM_LAYERS * 36 * 8 * 64 + 255) / 256, 256, 0, stream>>>(V, W_loop, Bf);
    k_input<<<N_NODES / 16, 128, 0, stream>>>(feat, qrel, rel_emb, W_in, b_in, h16a, er);

    unsigned short* h16cur = h16a;
    unsigned short* h16next = h16b;
    for (int l = 0; l < NUM_LAYERS; l++) {
        const float* comp_l = comp + (size_t)l * NUM_RELS * NUM_BASES;
        const unsigned short* Bfl = Bf + (size_t)l * 36 * 8 * 64 * 8;
        const float* bl = b_loop + (size_t)l * HID;
        k_fused2<<<(N_NODES + 31) / 32, 512, 0, stream>>>(h16cur, comp_l, row_start,
                                                          edge_p, Bfl, bl, h16next);
        unsigned short* tmp16 = h16cur; h16cur = h16next; h16next = tmp16;
    }

    k_score<<<N_NODES / 16, 128, 0, stream>>>(h16cur, er, W_attn, b_attn, w_sc, b_sc, af);
    k_starts<<<1, 256, 0, stream>>>(gid, starts);
    k_pool<<<NUM_GRAPHS, 128, 0, stream>>>(h16cur, af, starts, w_out, b_out, out);
}